// Round 7
// baseline (156.378 us; speedup 1.0000x reference)
//
#include <hip/hip_runtime.h>
#include <hip/hip_bf16.h>
#include <cstdint>
#include <cstddef>

#define T_DIM 2048
#define C_DIM 1024
#define NH 16
#define HS 64
#define KSP 64

// QKV/o-proj GEMM: 128x64 tile, BK=128, XOR-swizzled LDS, global_load_lds
#define GBM 128
#define GBN 64
#define GBK 128

// attention tiling: ATB=16 consecutive t's per block, 2 heads (1 per wave).
// union(tile) = sel(t0) UNION {t0+1..t0+15} (prefix property) -> positional
// slots 0..78; slot 79 = pad (row t0 data, cnt=0 -> masked).
// Union + per-t multiplicity table hoisted to prep_kernel (once per tile,
// was rebuilt by all 8 head-pair blocks).
#define ATB 16
#define NTILE (T_DIM / ATB)  // 128
#define KLS 64    // Kl row stride (shorts): 128B rows + XOR swizzle -> ~2-way
#define VTS 102   // Vt row stride (shorts): odd u32-stride 51 -> writes ~2-way
#define PLS 96    // Pl row stride (shorts): 192B rows, 16B-aligned b128 reads
// LDS: 2*80*64*2 + 2*64*102*2 + 2*16*96*2 + 160 = 52.9 KB -> 3 blocks/CU

typedef short short8 __attribute__((ext_vector_type(8)));
typedef float f32x4 __attribute__((ext_vector_type(4)));
typedef _Float16 half8 __attribute__((ext_vector_type(8)));

__device__ __forceinline__ unsigned short f2bfu(float f) {
  unsigned u = __builtin_bit_cast(unsigned, f);
  unsigned r = (u + 0x7fffu + ((u >> 16) & 1u)) >> 16;
  return (unsigned short)r;
}
__device__ __forceinline__ unsigned short f2h(float f) {
  _Float16 h = (_Float16)f;
  return __builtin_bit_cast(unsigned short, h);
}

#define GLOAD_LDS16(gp, lp)                                                  \
  __builtin_amdgcn_global_load_lds(                                          \
      (const __attribute__((address_space(1))) void*)(gp),                   \
      (__attribute__((address_space(3))) void*)(lp), 16, 0, 0)

// ---- launch 1: key_scores (blocks [0,512)) + f32->bf16 conversion (rest) ----
#define NSCORE (T_DIM / 4)  // 512
#define NCONV ((T_DIM * C_DIM + 4 * C_DIM * C_DIM) / 4 / 256)  // 6144
__global__ __launch_bounds__(256) void convert_scores_kernel(
    const float* __restrict__ x, const float* __restrict__ Wq,
    const float* __restrict__ Wk, const float* __restrict__ Wv,
    const float* __restrict__ Wo, const float* __restrict__ Wks,
    const float* __restrict__ bks,
    unsigned short* __restrict__ xb, unsigned short* __restrict__ Wqb,
    unsigned short* __restrict__ Wkb, unsigned short* __restrict__ Wvb,
    unsigned short* __restrict__ Wob, float* __restrict__ scores) {
  if (blockIdx.x < NSCORE) {
    const int t = blockIdx.x * 4 + (threadIdx.x >> 6);
    const int lane = threadIdx.x & 63;
    const float* xrow = x + (size_t)t * C_DIM;
    float acc = 0.f;
    #pragma unroll 4
    for (int i = lane; i < C_DIM; i += 64)
      acc += xrow[i] * Wks[i];
    #pragma unroll
    for (int o = 32; o; o >>= 1) acc += __shfl_xor(acc, o);
    if (lane == 0) scores[t] = acc + bks[0];
    return;
  }
  const int i = (blockIdx.x - NSCORE) * 256 + threadIdx.x;
  const int NX4 = T_DIM * C_DIM / 4;
  const int NW4 = C_DIM * C_DIM / 4;
  const float* src;
  unsigned short* dst;
  int j = i;
  if (j < NX4) { src = x; dst = xb; }
  else {
    j -= NX4;
    int w = j / NW4;
    j -= w * NW4;
    src = (w == 0) ? Wq : (w == 1) ? Wk : (w == 2) ? Wv : Wo;
    dst = (w == 0) ? Wqb : (w == 1) ? Wkb : (w == 2) ? Wvb : Wob;
  }
  float4 f = reinterpret_cast<const float4*>(src)[j];
  ushort4 o;
  o.x = f2bfu(f.x); o.y = f2bfu(f.y); o.z = f2bfu(f.z); o.w = f2bfu(f.w);
  reinterpret_cast<ushort4*>(dst)[j] = o;
}

// ---- GEMM body: 128x64 tile, BK=128; LDS passed in (shared arena) ----
__device__ __forceinline__ void gemm_body_128x64(
    const unsigned short* __restrict__ A, const unsigned short* __restrict__ W,
    f32x4 acc[4][2], int bm, int bn, int tid,
    unsigned short* As, unsigned short* Ws) {
  const int w = tid >> 6, lane = tid & 63;
  const int quad = lane >> 4, r = lane & 15;
  const int wm = (w >> 1) * 64, wn = (w & 1) * 32;
  const int sub = lane >> 4;
  const int c = lane & 15;
  const unsigned short* Arow[8];
  const unsigned short* Wrow[4];
  #pragma unroll
  for (int i = 0; i < 8; ++i) {
    const int row = w * 32 + i * 4 + sub;
    Arow[i] = A + (size_t)(bm * GBM + row) * C_DIM + ((c ^ (row & 7)) * 8);
  }
  #pragma unroll
  for (int i = 0; i < 4; ++i) {
    const int row = w * 16 + i * 4 + sub;
    Wrow[i] = W + (size_t)(bn * GBN + row) * C_DIM + ((c ^ (row & 7)) * 8);
  }
  for (int kb = 0; kb < C_DIM; kb += GBK) {
    #pragma unroll
    for (int i = 0; i < 8; ++i)
      GLOAD_LDS16(Arow[i] + kb, &As[(w * 32 + i * 4) * GBK]);
    #pragma unroll
    for (int i = 0; i < 4; ++i)
      GLOAD_LDS16(Wrow[i] + kb, &Ws[(w * 16 + i * 4) * GBK]);
    __syncthreads();
    #pragma unroll
    for (int ks = 0; ks < 4; ++ks) {
      const int pc = ((ks * 4 + quad) ^ (r & 7)) * 8;
      short8 af[4], bfr[2];
      #pragma unroll
      for (int mi = 0; mi < 4; ++mi)
        af[mi] = *reinterpret_cast<const short8*>(&As[(wm + mi * 16 + r) * GBK + pc]);
      #pragma unroll
      for (int ni = 0; ni < 2; ++ni)
        bfr[ni] = *reinterpret_cast<const short8*>(&Ws[(wn + ni * 16 + r) * GBK + pc]);
      #pragma unroll
      for (int mi = 0; mi < 4; ++mi)
        #pragma unroll
        for (int ni = 0; ni < 2; ++ni)
          acc[mi][ni] = __builtin_amdgcn_mfma_f32_16x16x32_bf16(af[mi], bfr[ni], acc[mi][ni], 0, 0, 0);
    }
    __syncthreads();
  }
}

// ---- launch 2: rank_sort (blocks [0,512)) + fused QKV GEMM (rest). ----
#define NRANK (T_DIM / 4)  // 512
__global__ __launch_bounds__(256) void gemm_qkv_rank_kernel(
    const unsigned short* __restrict__ A,
    const unsigned short* __restrict__ Wq, const unsigned short* __restrict__ Wk,
    const unsigned short* __restrict__ Wv,
    const float* __restrict__ bq, const float* __restrict__ bk,
    const float* __restrict__ bv,
    unsigned short* __restrict__ qo, unsigned short* __restrict__ ko,
    unsigned short* __restrict__ vo,
    const float* __restrict__ scores, int* __restrict__ sorted_idx) {
  __shared__ unsigned short lds[(GBM + GBN) * GBK];  // 48 KB arena
  const int tid = threadIdx.x;
  if (blockIdx.x < NRANK) {
    // rank-by-counting sort: one wave per element, lane-parallel scan
    float* ss = reinterpret_cast<float*>(lds);  // first 8 KB of arena
    for (int j = tid; j < T_DIM; j += 256) ss[j] = scores[j];
    __syncthreads();
    const int w = tid >> 6, lane = tid & 63;
    const int i = blockIdx.x * 4 + w;
    const float si = ss[i];
    int rank = 0;
    #pragma unroll
    for (int step = 0; step < T_DIM / 64; ++step) {
      const int j = step * 64 + lane;
      const float sj = ss[j];
      rank += (int)((sj > si) || (sj == si && j < i));
    }
    #pragma unroll
    for (int o = 32; o; o >>= 1) rank += __shfl_xor(rank, o);
    if (lane == 0) sorted_idx[rank] = i;
    return;
  }
  const int bid = blockIdx.x - NRANK;
  const int per = (T_DIM / GBM) * (C_DIM / GBN);  // 256
  const int which = bid / per;
  const int rem = bid % per;
  const int bm = rem / (C_DIM / GBN);
  const int bn = rem % (C_DIM / GBN);
  const unsigned short* W = (which == 0) ? Wq : (which == 1) ? Wk : Wv;
  const float* bias = (which == 0) ? bq : (which == 1) ? bk : bv;
  unsigned short* out = (which == 0) ? qo : (which == 1) ? ko : vo;
  f32x4 acc[4][2] = {};
  gemm_body_128x64(A, W, acc, bm, bn, tid, lds, lds + GBM * GBK);
  const int w = tid >> 6, lane = tid & 63;
  const int quad = lane >> 4, r = lane & 15;
  const int wm = (w >> 1) * 64, wn = (w & 1) * 32;
  #pragma unroll
  for (int mi = 0; mi < 4; ++mi) {
    #pragma unroll
    for (int ni = 0; ni < 2; ++ni) {
      const int col = bn * GBN + wn + ni * 16 + r;
      const float bf = bias[col];
      #pragma unroll
      for (int i = 0; i < 4; ++i) {
        const int row = bm * GBM + wm + mi * 16 + quad * 4 + i;
        const float val = acc[mi][ni][i] + bf;
        // q,k,v all f16 (MFMA f16 path in attn; f16 V >= bf16 precision)
        out[(size_t)row * C_DIM + col] = f2h(val);
      }
    }
  }
}

// ---- launch 5: output projection GEMM, fp32 out, 128x64 tile ----
__global__ __launch_bounds__(256) void gemm_o_f32_kernel(
    const unsigned short* __restrict__ A, const unsigned short* __restrict__ W,
    const float* __restrict__ bias, float* __restrict__ out) {
  __shared__ unsigned short lds[(GBM + GBN) * GBK];  // 48 KB arena
  const int tid = threadIdx.x;
  const int bm = blockIdx.x / (C_DIM / GBN);
  const int bn = blockIdx.x % (C_DIM / GBN);
  f32x4 acc[4][2] = {};
  gemm_body_128x64(A, W, acc, bm, bn, tid, lds, lds + GBM * GBK);
  const int w = tid >> 6, lane = tid & 63;
  const int quad = lane >> 4, r = lane & 15;
  const int wm = (w >> 1) * 64, wn = (w & 1) * 32;
  #pragma unroll
  for (int mi = 0; mi < 4; ++mi) {
    #pragma unroll
    for (int ni = 0; ni < 2; ++ni) {
      const int col = bn * GBN + wn + ni * 16 + r;
      const float bf = bias[col];
      #pragma unroll
      for (int i = 0; i < 4; ++i) {
        const int row = bm * GBM + wm + mi * 16 + quad * 4 + i;
        out[(size_t)row * C_DIM + col] = acc[mi][ni][i] + bf;
      }
    }
  }
}

// ---- launch 3: per-tile prep (one block per 16-t tile).
// Fuses selection scan (4 t's per wave share one chunk-load stream, early
// exit on smallest t = last to finish) + positional union + multiplicity
// table. Outputs urows[80] u16 and cnt[16][80] u8 per tile — consumed by all
// 8 head-pair attn blocks (was rebuilt 8x in attn). ----
__global__ __launch_bounds__(256) void prep_kernel(
    const int* __restrict__ sorted_idx,
    unsigned short* __restrict__ urows_g,   // [NTILE][80]
    unsigned char* __restrict__ cnt_g) {    // [NTILE][16][80]
  __shared__ unsigned short rows_tab[ATB][KSP];  // 2 KB
  __shared__ unsigned char map_s[T_DIM];         // 2 KB (slots < 80 fit u8)
  __shared__ unsigned int cnt_l[16 * 80];        // 5 KB
  const int tile = blockIdx.x;
  const int t0 = tile * ATB;
  const int tid = threadIdx.x;
  const int w = tid >> 6, lane = tid & 63;
  if (t0 <= 48) {
    // whole tile has t <= 63: rows 0..t-1 once, row t duplicated (clamped
    // -inf picks) — reference top_k semantics.
    #pragma unroll
    for (int li = 0; li < 4; ++li) {
      const int t = t0 + w * 4 + li;
      rows_tab[w * 4 + li][lane] = (unsigned short)((lane < t) ? lane : t);
    }
  } else {
    const unsigned long long lt_mask = (1ull << lane) - 1ull;
    const int tw = t0 + w * 4;
    int c4[4] = {0, 0, 0, 0};
    for (int c = 0; c < T_DIM / 64 && c4[0] < KSP; ++c) {
      int s = sorted_idx[c * 64 + lane];
      s = (s < 0) ? 0 : (s > T_DIM - 1 ? T_DIM - 1 : s);
      #pragma unroll
      for (int li = 0; li < 4; ++li) {
        const bool ok = (s <= tw + li);
        const unsigned long long mm = __ballot(ok);
        const int pos = c4[li] + __popcll(mm & lt_mask);
        if (ok && pos < KSP) rows_tab[w * 4 + li][pos] = (unsigned short)s;
        c4[li] += __popcll(mm);
      }
    }
  }
  for (int i = tid; i < 16 * 80; i += 256) cnt_l[i] = 0u;
  __syncthreads();
  // positional union: slot j<64 = sel(t0)[j], 64..78 = t0+1..t0+15, 79 = pad
  if (tid < KSP) {
    const int r0 = rows_tab[0][tid];
    map_s[r0] = (unsigned char)tid;  // dup rows (t0<64) race benign
    urows_g[(size_t)tile * 80 + tid] = (unsigned short)r0;
  } else if (tid < 79) {
    const int row = t0 + 1 + (tid - KSP);
    map_s[row] = (unsigned char)tid;
    urows_g[(size_t)tile * 80 + tid] = (unsigned short)row;
  } else if (tid == 79) {
    urows_g[(size_t)tile * 80 + 79] = (unsigned short)t0;  // pad: cnt=0
  }
  __syncthreads();
  if (t0 < 64) {
    #pragma unroll
    for (int e = 0; e < 4; ++e) {
      const int idx = tid + e * 256;
      atomicAdd(&cnt_l[(idx >> 6) * 80 + map_s[rows_tab[idx >> 6][idx & 63]]], 1u);
    }
  } else {
    #pragma unroll
    for (int e = 0; e < 4; ++e) {
      const int idx = tid + e * 256;
      cnt_l[(idx >> 6) * 80 + map_s[rows_tab[idx >> 6][idx & 63]]] = 1u;
    }
  }
  __syncthreads();
  unsigned* cg = reinterpret_cast<unsigned*>(cnt_g + (size_t)tile * 1280);
  for (int i = tid; i < 320; i += 256)
    cg[i] = (cnt_l[4 * i] & 0xffu) | ((cnt_l[4 * i + 1] & 0xffu) << 8) |
            ((cnt_l[4 * i + 2] & 0xffu) << 16) | ((cnt_l[4 * i + 3] & 0xffu) << 24);
}

// ---- launch 4: MFMA sparse attention (prep-hoisted, slim LDS).
// Block = (16 t's, 2 heads), 128 threads. 52.9 KB LDS -> 3 blocks/CU (was
// 73.4 KB / 2). S^T = K @ Q^T (10 mfma) -> lane-local softmax w/ cnt bias
// from global -> P f16 via Pl roundtrip -> O^T = Vt @ P (12 mfma). ----
__global__ __launch_bounds__(128) void attn_kernel(
    const unsigned short* __restrict__ q, const unsigned short* __restrict__ k,
    const unsigned short* __restrict__ v,
    const unsigned short* __restrict__ urows_g,
    const unsigned char* __restrict__ cnt_g,
    unsigned short* __restrict__ attn_out) {
  __shared__ unsigned short Kl[2][80 * KLS];   // 2 x 10240 B
  __shared__ unsigned short Vt[2][64 * VTS];   // 2 x 13056 B
  __shared__ unsigned short Pl[2][16 * PLS];   // 2 x 3072 B
  __shared__ unsigned short urows[80];         // 160 B
  const int tb = blockIdx.x >> 3;
  const int hg = blockIdx.x & 7;
  const int t0 = tb * ATB;
  const int tid = threadIdx.x;
  const int w = tid >> 6, lane = tid & 63;
  const int qd = lane >> 4;      // quad
  const int r = lane & 15;
  const int h = hg * 2 + w;
  if (tid < 80) urows[tid] = urows_g[(size_t)tb * 80 + tid];
  // hoist Q B-frags (global f16): lane (qd,r) holds Q[t0+r][kc*32+qd*8 ..+7]
  uint4 qf[2];
  #pragma unroll
  for (int kc = 0; kc < 2; ++kc)
    qf[kc] = *reinterpret_cast<const uint4*>(
        q + (size_t)(t0 + r) * C_DIM + h * HS + kc * 32 + qd * 8);
  __syncthreads();

  // gather union K/V head slices (row pairs per lane-octet)
  {
    const int e8 = lane & 7;
    const int pr = lane >> 3;  // row-pair id 0..7
    #pragma unroll
    for (int sb = 0; sb < 5; ++sb) {
      const int s0 = sb * 16 + pr * 2;
      const int row0 = urows[s0], row1 = urows[s0 + 1];
      const size_t g0 = (size_t)row0 * C_DIM + h * HS + e8 * 8;
      const size_t g1 = (size_t)row1 * C_DIM + h * HS + e8 * 8;
      const uint4 k0 = *reinterpret_cast<const uint4*>(k + g0);
      const uint4 k1 = *reinterpret_cast<const uint4*>(k + g1);
      const uint4 v0 = *reinterpret_cast<const uint4*>(v + g0);
      const uint4 v1 = *reinterpret_cast<const uint4*>(v + g1);
      *reinterpret_cast<uint4*>(&Kl[w][s0 * KLS + ((e8 ^ (s0 & 7)) * 8)]) = k0;
      *reinterpret_cast<uint4*>(&Kl[w][(s0 + 1) * KLS + ((e8 ^ ((s0 + 1) & 7)) * 8)]) = k1;
      const unsigned* v0w = reinterpret_cast<const unsigned*>(&v0);
      const unsigned* v1w = reinterpret_cast<const unsigned*>(&v1);
      // transpose-scatter: Vt[d][s0..s0+1] as one u32 (pair-packed)
      #pragma unroll
      for (int dd = 0; dd < 8; ++dd) {
        const unsigned lo = (v0w[dd >> 1] >> ((dd & 1) * 16)) & 0xffffu;
        const unsigned hi = (v1w[dd >> 1] >> ((dd & 1) * 16)) & 0xffffu;
        *reinterpret_cast<unsigned*>(&Vt[w][(e8 * 8 + dd) * VTS + s0]) =
            lo | (hi << 16);
      }
    }
    // zero Vt pad cols u=80..95 (k-chunk 2 covers u 64..95)
    #pragma unroll
    for (int z = 0; z < 8; ++z)
      *reinterpret_cast<unsigned*>(&Vt[w][lane * VTS + 80 + z * 2]) = 0u;
  }
  __syncthreads();

  // S^T = K @ Q^T; lane holds S[u=ut*16+qd*4+i][t=r]
  f32x4 s5[5] = {};
  #pragma unroll
  for (int ut = 0; ut < 5; ++ut) {
    #pragma unroll
    for (int kc = 0; kc < 2; ++kc) {
      const uint4 kw = *reinterpret_cast<const uint4*>(
          &Kl[w][(ut * 16 + r) * KLS + (((kc * 4 + qd) ^ (r & 7)) * 8)]);
      s5[ut] = __builtin_amdgcn_mfma_f32_16x16x32_f16(
          __builtin_bit_cast(half8, kw), __builtin_bit_cast(half8, qf[kc]),
          s5[ut], 0, 0, 0);
    }
  }
  // bias (mask/multiplicity from prep table) + row-max
  const unsigned char* cb = cnt_g + (size_t)tb * 1280 + r * 80;
  float mx = -3.0e38f;
  #pragma unroll
  for (int ut = 0; ut < 5; ++ut) {
    const unsigned c4 = *reinterpret_cast<const unsigned*>(cb + ut * 16 + qd * 4);
    #pragma unroll
    for (int i = 0; i < 4; ++i) {
      const unsigned cc = (c4 >> (8 * i)) & 0xffu;
      float lg = s5[ut][i] * 0.125f;
      lg = (cc == 0u) ? -3.0e38f
         : (cc == 1u) ? lg : (lg + __logf((float)cc));
      s5[ut][i] = lg;
      mx = fmaxf(mx, lg);
    }
  }
  mx = fmaxf(mx, __shfl_xor(mx, 16));
  mx = fmaxf(mx, __shfl_xor(mx, 32));
  float sum = 0.f;
  #pragma unroll
  for (int ut = 0; ut < 5; ++ut)
    #pragma unroll
    for (int i = 0; i < 4; ++i) {
      const float e = __expf(s5[ut][i] - mx);
      s5[ut][i] = e;
      sum += e;
    }
  sum += __shfl_xor(sum, 16);
  sum += __shfl_xor(sum, 32);
  const float rs = 1.0f / sum;
  // P -> f16 into Pl[t][u] (wave-local roundtrip; no barrier needed)
  #pragma unroll
  for (int ut = 0; ut < 5; ++ut) {
    const unsigned w0 = (unsigned)f2h(s5[ut][0] * rs) |
                        ((unsigned)f2h(s5[ut][1] * rs) << 16);
    const unsigned w1 = (unsigned)f2h(s5[ut][2] * rs) |
                        ((unsigned)f2h(s5[ut][3] * rs) << 16);
    unsigned* p32 = reinterpret_cast<unsigned*>(&Pl[w][r * PLS + ut * 16 + qd * 4]);
    p32[0] = w0;
    p32[1] = w1;
  }
  // zero Pl pad u=80..95 (4 shorts per quad)
  *reinterpret_cast<unsigned long long*>(&Pl[w][r * PLS + 80 + qd * 4]) = 0ull;
  // PV: O^T[d][t] = Vt @ P; A = Vt rows (d), B = Pl cols (t)
  f32x4 o4[4] = {};
  #pragma unroll
  for (int c = 0; c < 3; ++c) {
    const uint4 pw = *reinterpret_cast<const uint4*>(&Pl[w][r * PLS + c * 32 + qd * 8]);
    #pragma unroll
    for (int mt = 0; mt < 4; ++mt) {
      const unsigned short* vb_ = &Vt[w][(mt * 16 + r) * VTS + c * 32 + qd * 8];
      uint4 vw;
      vw.x = *reinterpret_cast<const unsigned*>(vb_);
      vw.y = *reinterpret_cast<const unsigned*>(vb_ + 2);
      vw.z = *reinterpret_cast<const unsigned*>(vb_ + 4);
      vw.w = *reinterpret_cast<const unsigned*>(vb_ + 6);
      o4[mt] = __builtin_amdgcn_mfma_f32_16x16x32_f16(
          __builtin_bit_cast(half8, vw), __builtin_bit_cast(half8, pw),
          o4[mt], 0, 0, 0);
    }
  }
  // store: lane holds O[t=r][d = mt*16 + qd*4 + i], bf16 out
  #pragma unroll
  for (int mt = 0; mt < 4; ++mt) {
    ushort4 ov;
    ov.x = f2bfu(o4[mt][0]); ov.y = f2bfu(o4[mt][1]);
    ov.z = f2bfu(o4[mt][2]); ov.w = f2bfu(o4[mt][3]);
    *reinterpret_cast<ushort4*>(
        attn_out + (size_t)(t0 + r) * C_DIM + h * HS + mt * 16 + qd * 4) = ov;
  }
}

extern "C" void kernel_launch(void* const* d_in, const int* in_sizes, int n_in,
                              void* d_out, int out_size, void* d_ws, size_t ws_size,
                              hipStream_t stream) {
  const float* x   = (const float*)d_in[0];
  const float* Wq  = (const float*)d_in[1];
  const float* bq  = (const float*)d_in[2];
  const float* Wk  = (const float*)d_in[3];
  const float* bk  = (const float*)d_in[4];
  const float* Wv  = (const float*)d_in[5];
  const float* bv  = (const float*)d_in[6];
  const float* Wo  = (const float*)d_in[7];
  const float* bo  = (const float*)d_in[8];
  const float* Wks = (const float*)d_in[9];
  const float* bks = (const float*)d_in[10];
  float* out = (float*)d_out;

  char* ws = (char*)d_ws;
  size_t off = 0;
  float* scores = (float*)(ws + off); off += 8192;
  int*   sorted = (int*)(ws + off);   off += 8192;
  unsigned short* urowsb = (unsigned short*)(ws + off); off += (size_t)NTILE * 80 * 2;
  unsigned char*  cntb   = (unsigned char*)(ws + off);  off += (size_t)NTILE * 1280;
  off = (off + 255) & ~(size_t)255;
  unsigned short* xb  = (unsigned short*)(ws + off); off += (size_t)T_DIM * C_DIM * 2;
  unsigned short* Wqb = (unsigned short*)(ws + off); off += (size_t)C_DIM * C_DIM * 2;
  unsigned short* Wkb = (unsigned short*)(ws + off); off += (size_t)C_DIM * C_DIM * 2;
  unsigned short* Wvb = (unsigned short*)(ws + off); off += (size_t)C_DIM * C_DIM * 2;
  unsigned short* Wob = (unsigned short*)(ws + off); off += (size_t)C_DIM * C_DIM * 2;
  unsigned short* qb  = (unsigned short*)(ws + off); off += (size_t)T_DIM * C_DIM * 2;
  unsigned short* kb  = (unsigned short*)(ws + off); off += (size_t)T_DIM * C_DIM * 2;
  unsigned short* vb  = (unsigned short*)(ws + off); off += (size_t)T_DIM * C_DIM * 2;
  unsigned short* ab  = xb;  // alias: xb dead after gemm_qkv

  // launch 1: conversion + scores
  convert_scores_kernel<<<NSCORE + NCONV, 256, 0, stream>>>(
      x, Wq, Wk, Wv, Wo, Wks, bks, xb, Wqb, Wkb, Wvb, Wob, scores);

  // launch 2: rank-sort (512 blocks) + fused QKV GEMM (768 blocks)
  gemm_qkv_rank_kernel<<<NRANK + 3 * (T_DIM / GBM) * (C_DIM / GBN), 256, 0,
                         stream>>>(
      xb, Wqb, Wkb, Wvb, bq, bk, bv, qb, kb, vb, scores, sorted);

  // launch 3: per-tile union + multiplicity prep (128 blocks)
  prep_kernel<<<NTILE, 256, 0, stream>>>(sorted, urowsb, cntb);

  // launch 4: MFMA attention (128 t-tiles x 8 head-pairs = 1024 blocks)
  attn_kernel<<<NTILE * (NH / 2), 128, 0, stream>>>(qb, kb, vb, urowsb, cntb, ab);

  // launch 5: output projection (256 blocks, 128x64)
  gemm_o_f32_kernel<<<(T_DIM / GBM) * (C_DIM / GBN), 256, 0, stream>>>(
      ab, Wob, bo, out);
}

// Round 8
// 146.503 us; speedup vs baseline: 1.0674x; 1.0674x over previous
//
#include <hip/hip_runtime.h>
#include <hip/hip_bf16.h>
#include <cstdint>
#include <cstddef>

#define T_DIM 2048
#define C_DIM 1024
#define NH 16
#define HS 64
#define KSP 64

// QKV GEMM: 128x64 tile, BK=128, XOR-swizzled LDS, global_load_lds staging
#define GBM 128
#define GBN 64
#define GBK 128
// o-proj GEMM: 64x64 tile (512 blocks = 2/CU) — R6 config (128x64 @1/CU regressed)
#define OBM 64
#define OBN 64

// attention tiling: ATB=16 consecutive t's per block, 2 heads (1 per wave).
// union(tile) = sel(t0) UNION {t0+1..t0+15} (prefix property) -> positional
// slots 0..78; slot 79 = pad (row t0 data, cnt=0 -> masked).
#define ATB 16
#define KLS 64    // Kl row stride (shorts): 128B + XOR swizzle -> ~2-way
#define VTS 102   // Vt row stride (shorts): odd u32-stride 51 -> ~2-way
#define PLS 96    // Pl row stride (shorts): 192B, 16B-aligned b128 reads

typedef short short8 __attribute__((ext_vector_type(8)));
typedef float f32x4 __attribute__((ext_vector_type(4)));
typedef _Float16 half8 __attribute__((ext_vector_type(8)));

__device__ __forceinline__ unsigned short f2bfu(float f) {
  unsigned u = __builtin_bit_cast(unsigned, f);
  unsigned r = (u + 0x7fffu + ((u >> 16) & 1u)) >> 16;
  return (unsigned short)r;
}
__device__ __forceinline__ unsigned short f2h(float f) {
  _Float16 h = (_Float16)f;
  return __builtin_bit_cast(unsigned short, h);
}

#define GLOAD_LDS16(gp, lp)                                                  \
  __builtin_amdgcn_global_load_lds(                                          \
      (const __attribute__((address_space(1))) void*)(gp),                   \
      (__attribute__((address_space(3))) void*)(lp), 16, 0, 0)

// ---- launch 1: key_scores (blocks [0,512)) + f32->bf16 conversion (rest) ----
#define NSCORE (T_DIM / 4)  // 512
#define NCONV ((T_DIM * C_DIM + 4 * C_DIM * C_DIM) / 4 / 256)  // 6144
__global__ __launch_bounds__(256) void convert_scores_kernel(
    const float* __restrict__ x, const float* __restrict__ Wq,
    const float* __restrict__ Wk, const float* __restrict__ Wv,
    const float* __restrict__ Wo, const float* __restrict__ Wks,
    const float* __restrict__ bks,
    unsigned short* __restrict__ xb, unsigned short* __restrict__ Wqb,
    unsigned short* __restrict__ Wkb, unsigned short* __restrict__ Wvb,
    unsigned short* __restrict__ Wob, float* __restrict__ scores) {
  if (blockIdx.x < NSCORE) {
    const int t = blockIdx.x * 4 + (threadIdx.x >> 6);
    const int lane = threadIdx.x & 63;
    const float* xrow = x + (size_t)t * C_DIM;
    float acc = 0.f;
    #pragma unroll 4
    for (int i = lane; i < C_DIM; i += 64)
      acc += xrow[i] * Wks[i];
    #pragma unroll
    for (int o = 32; o; o >>= 1) acc += __shfl_xor(acc, o);
    if (lane == 0) scores[t] = acc + bks[0];
    return;
  }
  const int i = (blockIdx.x - NSCORE) * 256 + threadIdx.x;
  const int NX4 = T_DIM * C_DIM / 4;
  const int NW4 = C_DIM * C_DIM / 4;
  const float* src;
  unsigned short* dst;
  int j = i;
  if (j < NX4) { src = x; dst = xb; }
  else {
    j -= NX4;
    int w = j / NW4;
    j -= w * NW4;
    src = (w == 0) ? Wq : (w == 1) ? Wk : (w == 2) ? Wv : Wo;
    dst = (w == 0) ? Wqb : (w == 1) ? Wkb : (w == 2) ? Wvb : Wob;
  }
  float4 f = reinterpret_cast<const float4*>(src)[j];
  ushort4 o;
  o.x = f2bfu(f.x); o.y = f2bfu(f.y); o.z = f2bfu(f.z); o.w = f2bfu(f.w);
  reinterpret_cast<ushort4*>(dst)[j] = o;
}

// ---- GEMM body: 128x64 tile, BK=128; LDS passed in (shared arena) ----
__device__ __forceinline__ void gemm_body_128x64(
    const unsigned short* __restrict__ A, const unsigned short* __restrict__ W,
    f32x4 acc[4][2], int bm, int bn, int tid,
    unsigned short* As, unsigned short* Ws) {
  const int w = tid >> 6, lane = tid & 63;
  const int quad = lane >> 4, r = lane & 15;
  const int wm = (w >> 1) * 64, wn = (w & 1) * 32;
  const int sub = lane >> 4;
  const int c = lane & 15;
  const unsigned short* Arow[8];
  const unsigned short* Wrow[4];
  #pragma unroll
  for (int i = 0; i < 8; ++i) {
    const int row = w * 32 + i * 4 + sub;
    Arow[i] = A + (size_t)(bm * GBM + row) * C_DIM + ((c ^ (row & 7)) * 8);
  }
  #pragma unroll
  for (int i = 0; i < 4; ++i) {
    const int row = w * 16 + i * 4 + sub;
    Wrow[i] = W + (size_t)(bn * GBN + row) * C_DIM + ((c ^ (row & 7)) * 8);
  }
  for (int kb = 0; kb < C_DIM; kb += GBK) {
    #pragma unroll
    for (int i = 0; i < 8; ++i)
      GLOAD_LDS16(Arow[i] + kb, &As[(w * 32 + i * 4) * GBK]);
    #pragma unroll
    for (int i = 0; i < 4; ++i)
      GLOAD_LDS16(Wrow[i] + kb, &Ws[(w * 16 + i * 4) * GBK]);
    __syncthreads();
    #pragma unroll
    for (int ks = 0; ks < 4; ++ks) {
      const int pc = ((ks * 4 + quad) ^ (r & 7)) * 8;
      short8 af[4], bfr[2];
      #pragma unroll
      for (int mi = 0; mi < 4; ++mi)
        af[mi] = *reinterpret_cast<const short8*>(&As[(wm + mi * 16 + r) * GBK + pc]);
      #pragma unroll
      for (int ni = 0; ni < 2; ++ni)
        bfr[ni] = *reinterpret_cast<const short8*>(&Ws[(wn + ni * 16 + r) * GBK + pc]);
      #pragma unroll
      for (int mi = 0; mi < 4; ++mi)
        #pragma unroll
        for (int ni = 0; ni < 2; ++ni)
          acc[mi][ni] = __builtin_amdgcn_mfma_f32_16x16x32_bf16(af[mi], bfr[ni], acc[mi][ni], 0, 0, 0);
    }
    __syncthreads();
  }
}

// ---- launch 2: rank_sort (blocks [0,512)) + fused QKV GEMM (rest). ----
#define NRANK (T_DIM / 4)  // 512
__global__ __launch_bounds__(256) void gemm_qkv_rank_kernel(
    const unsigned short* __restrict__ A,
    const unsigned short* __restrict__ Wq, const unsigned short* __restrict__ Wk,
    const unsigned short* __restrict__ Wv,
    const float* __restrict__ bq, const float* __restrict__ bk,
    const float* __restrict__ bv,
    unsigned short* __restrict__ qo, unsigned short* __restrict__ ko,
    unsigned short* __restrict__ vo,
    const float* __restrict__ scores, int* __restrict__ sorted_idx) {
  __shared__ unsigned short lds[(GBM + GBN) * GBK];  // 48 KB arena
  const int tid = threadIdx.x;
  if (blockIdx.x < NRANK) {
    // rank-by-counting sort: one wave per element, lane-parallel scan
    float* ss = reinterpret_cast<float*>(lds);  // first 8 KB of arena
    for (int j = tid; j < T_DIM; j += 256) ss[j] = scores[j];
    __syncthreads();
    const int w = tid >> 6, lane = tid & 63;
    const int i = blockIdx.x * 4 + w;
    const float si = ss[i];
    int rank = 0;
    #pragma unroll
    for (int step = 0; step < T_DIM / 64; ++step) {
      const int j = step * 64 + lane;
      const float sj = ss[j];
      rank += (int)((sj > si) || (sj == si && j < i));
    }
    #pragma unroll
    for (int o = 32; o; o >>= 1) rank += __shfl_xor(rank, o);
    if (lane == 0) sorted_idx[rank] = i;
    return;
  }
  const int bid = blockIdx.x - NRANK;
  const int per = (T_DIM / GBM) * (C_DIM / GBN);  // 256
  const int which = bid / per;
  const int rem = bid % per;
  const int bm = rem / (C_DIM / GBN);
  const int bn = rem % (C_DIM / GBN);
  const unsigned short* W = (which == 0) ? Wq : (which == 1) ? Wk : Wv;
  const float* bias = (which == 0) ? bq : (which == 1) ? bk : bv;
  unsigned short* out = (which == 0) ? qo : (which == 1) ? ko : vo;
  f32x4 acc[4][2] = {};
  gemm_body_128x64(A, W, acc, bm, bn, tid, lds, lds + GBM * GBK);
  const int w = tid >> 6, lane = tid & 63;
  const int quad = lane >> 4, r = lane & 15;
  const int wm = (w >> 1) * 64, wn = (w & 1) * 32;
  #pragma unroll
  for (int mi = 0; mi < 4; ++mi) {
    #pragma unroll
    for (int ni = 0; ni < 2; ++ni) {
      const int col = bn * GBN + wn + ni * 16 + r;
      const float bf = bias[col];
      #pragma unroll
      for (int i = 0; i < 4; ++i) {
        const int row = bm * GBM + wm + mi * 16 + quad * 4 + i;
        const float val = acc[mi][ni][i] + bf;
        // q,k,v all f16 (MFMA f16 path in attn; f16 V >= bf16 precision)
        out[(size_t)row * C_DIM + col] = f2h(val);
      }
    }
  }
}

// ---- o-proj GEMM body: 64x64 tile, BK=128 (R6-verified) ----
__device__ __forceinline__ void gemm_body_64x64(
    const unsigned short* __restrict__ A, const unsigned short* __restrict__ W,
    f32x4 acc[2][2], int bm, int bn, int tid) {
  __shared__ unsigned short As[OBM * GBK];  // 16 KB
  __shared__ unsigned short Ws[OBN * GBK];  // 16 KB
  const int w = tid >> 6, lane = tid & 63;
  const int quad = lane >> 4, r = lane & 15;
  const int wm = (w >> 1) * 32, wn = (w & 1) * 32;
  const int sub = lane >> 4;
  const int c = lane & 15;
  const unsigned short* Arow[4];
  const unsigned short* Wrow[4];
  #pragma unroll
  for (int i = 0; i < 4; ++i) {
    const int row = w * 16 + i * 4 + sub;
    Arow[i] = A + (size_t)(bm * OBM + row) * C_DIM + ((c ^ (row & 7)) * 8);
    Wrow[i] = W + (size_t)(bn * OBN + row) * C_DIM + ((c ^ (row & 7)) * 8);
  }
  for (int kb = 0; kb < C_DIM; kb += GBK) {
    #pragma unroll
    for (int i = 0; i < 4; ++i)
      GLOAD_LDS16(Arow[i] + kb, &As[(w * 16 + i * 4) * GBK]);
    #pragma unroll
    for (int i = 0; i < 4; ++i)
      GLOAD_LDS16(Wrow[i] + kb, &Ws[(w * 16 + i * 4) * GBK]);
    __syncthreads();
    #pragma unroll
    for (int ks = 0; ks < 4; ++ks) {
      const int pc = ((ks * 4 + quad) ^ (r & 7)) * 8;
      short8 af[2], bfr[2];
      #pragma unroll
      for (int mi = 0; mi < 2; ++mi)
        af[mi] = *reinterpret_cast<const short8*>(&As[(wm + mi * 16 + r) * GBK + pc]);
      #pragma unroll
      for (int ni = 0; ni < 2; ++ni)
        bfr[ni] = *reinterpret_cast<const short8*>(&Ws[(wn + ni * 16 + r) * GBK + pc]);
      #pragma unroll
      for (int mi = 0; mi < 2; ++mi)
        #pragma unroll
        for (int ni = 0; ni < 2; ++ni)
          acc[mi][ni] = __builtin_amdgcn_mfma_f32_16x16x32_bf16(af[mi], bfr[ni], acc[mi][ni], 0, 0, 0);
    }
    __syncthreads();
  }
}

// ---- launch 5: output projection GEMM, fp32 out, 64x64 tile ----
__global__ __launch_bounds__(256) void gemm_o_f32_kernel(
    const unsigned short* __restrict__ A, const unsigned short* __restrict__ W,
    const float* __restrict__ bias, float* __restrict__ out) {
  const int tid = threadIdx.x;
  const int bm = blockIdx.x / (C_DIM / OBN);
  const int bn = blockIdx.x % (C_DIM / OBN);
  f32x4 acc[2][2] = {};
  gemm_body_64x64(A, W, acc, bm, bn, tid);
  const int w = tid >> 6, lane = tid & 63;
  const int quad = lane >> 4, r = lane & 15;
  const int wm = (w >> 1) * 32, wn = (w & 1) * 32;
  #pragma unroll
  for (int mi = 0; mi < 2; ++mi) {
    #pragma unroll
    for (int ni = 0; ni < 2; ++ni) {
      const int col = bn * OBN + wn + ni * 16 + r;
      const float bf = bias[col];
      #pragma unroll
      for (int i = 0; i < 4; ++i) {
        const int row = bm * OBM + wm + mi * 16 + quad * 4 + i;
        out[(size_t)row * C_DIM + col] = acc[mi][ni][i] + bf;
      }
    }
  }
}

// ---- launch 3: per-t top-64 selection (one wave per t, u16 row indices) ----
__global__ __launch_bounds__(256) void select_kernel(
    const int* __restrict__ sorted_idx, unsigned short* __restrict__ sel) {
  const int tid = threadIdx.x;
  const int w = tid >> 6, lane = tid & 63;
  const int t = blockIdx.x * 4 + w;
  unsigned short* dst = sel + (size_t)t * KSP;
  if (t <= 63) {
    // reference semantics: rows 0..t-1 once, row t duplicated (clamped -inf picks)
    dst[lane] = (unsigned short)((lane < t) ? lane : t);
    return;
  }
  const unsigned long long lt_mask = (1ull << lane) - 1ull;
  int count = 0;
  for (int c = 0; c < T_DIM / 64 && count < KSP; ++c) {
    int s = sorted_idx[c * 64 + lane];
    s = (s < 0) ? 0 : (s > T_DIM - 1 ? T_DIM - 1 : s);
    const bool ok = (s <= t);
    const unsigned long long mm = __ballot(ok);
    const int pos = count + __popcll(mm & lt_mask);
    if (ok && pos < KSP) dst[pos] = (unsigned short)s;
    count += __popcll(mm);
  }
}

// ---- launch 4: MFMA sparse attention, slim LDS (52.9 KB -> 3 blocks/CU).
// R6 structure (inline union from sel) with: KLS 64+XOR, VTS 102, PLS 96
// (all R7-verified), and map/cnt as u8 OVERLAID on the Pl region (dead
// before Pl is written; extra barrier protects the overlay). cnt for the
// four t0<64 tiles computed analytically (no atomics). ----
__global__ __launch_bounds__(128) void attn_kernel(
    const unsigned short* __restrict__ q, const unsigned short* __restrict__ k,
    const unsigned short* __restrict__ v, const unsigned short* __restrict__ sel,
    unsigned short* __restrict__ attn_out) {
  // arena carve:
  //   [0,20480)      Kl: 2 x 80 x 64 shorts (XOR-swizzled rows)
  //   [20480,46592)  Vt: 2 x 64 x 102 shorts
  //   [46592,52736)  Pl: 2 x 16 x 96 shorts; overlay map8[2048]+cnt8[1280]
  //   [52736,52896)  urows[80]
  __shared__ __align__(16) unsigned char arena[52896];
  unsigned short* KlB = reinterpret_cast<unsigned short*>(arena);
  unsigned short* VtB = reinterpret_cast<unsigned short*>(arena + 20480);
  unsigned short* PlB = reinterpret_cast<unsigned short*>(arena + 46592);
  unsigned char* map8 = arena + 46592;
  unsigned char* cnt8 = arena + 46592 + 2048;
  unsigned short* urows = reinterpret_cast<unsigned short*>(arena + 52736);
  const int tb = blockIdx.x >> 3;
  const int hg = blockIdx.x & 7;
  const int t0 = tb * ATB;
  const int tid = threadIdx.x;
  const int w = tid >> 6, lane = tid & 63;
  const int qd = lane >> 4;      // quad
  const int r = lane & 15;
  const int h = hg * 2 + w;
  unsigned short* Klw = KlB + w * 80 * KLS;
  unsigned short* Vtw = VtB + w * 64 * VTS;
  unsigned short* Plw = PlB + w * 16 * PLS;

  // hoist Q B-frags (global f16): lane (qd,r) holds Q[t0+r][kc*32+qd*8 ..+7]
  uint4 qf[2];
  #pragma unroll
  for (int kc = 0; kc < 2; ++kc)
    qf[kc] = *reinterpret_cast<const uint4*>(
        q + (size_t)(t0 + r) * C_DIM + h * HS + kc * 32 + qd * 8);

  // phase A: positional union (slots 0..78 + pad 79), map build (t0>=64),
  // cnt zero-init (t0>=64 path only; analytic path overwrites all entries)
  if (tid < KSP) {
    const int r0 = sel[(size_t)t0 * KSP + tid];
    urows[tid] = (unsigned short)r0;
    if (t0 >= 64) map8[r0] = (unsigned char)tid;  // rows distinct -> no race
  } else if (tid < 79) {
    const int row = t0 + 1 + (tid - KSP);
    urows[tid] = (unsigned short)row;
    if (t0 >= 64) map8[row] = (unsigned char)tid;
  } else if (tid == 79) {
    urows[79] = (unsigned short)t0;   // pad slot: real data, cnt=0 -> masked
  }
  if (t0 >= 64) {
    for (int i = tid; i < 320; i += 128)
      reinterpret_cast<unsigned*>(cnt8)[i] = 0u;
  }
  __syncthreads();

  // phase B: per-wave K/V gather + cooperative cnt build
  {
    const int e8 = lane & 7;
    const int pr = lane >> 3;  // row-pair id 0..7
    #pragma unroll
    for (int sb = 0; sb < 5; ++sb) {
      const int s0 = sb * 16 + pr * 2;
      const int row0 = urows[s0], row1 = urows[s0 + 1];
      const size_t g0 = (size_t)row0 * C_DIM + h * HS + e8 * 8;
      const size_t g1 = (size_t)row1 * C_DIM + h * HS + e8 * 8;
      const uint4 k0 = *reinterpret_cast<const uint4*>(k + g0);
      const uint4 k1 = *reinterpret_cast<const uint4*>(k + g1);
      const uint4 v0 = *reinterpret_cast<const uint4*>(v + g0);
      const uint4 v1 = *reinterpret_cast<const uint4*>(v + g1);
      *reinterpret_cast<uint4*>(&Klw[s0 * KLS + ((e8 ^ (s0 & 7)) * 8)]) = k0;
      *reinterpret_cast<uint4*>(&Klw[(s0 + 1) * KLS + ((e8 ^ ((s0 + 1) & 7)) * 8)]) = k1;
      const unsigned* v0w = reinterpret_cast<const unsigned*>(&v0);
      const unsigned* v1w = reinterpret_cast<const unsigned*>(&v1);
      // transpose-scatter: Vt[d][s0..s0+1] as one u32 (pair-packed)
      #pragma unroll
      for (int dd = 0; dd < 8; ++dd) {
        const unsigned lo = (v0w[dd >> 1] >> ((dd & 1) * 16)) & 0xffffu;
        const unsigned hi = (v1w[dd >> 1] >> ((dd & 1) * 16)) & 0xffffu;
        *reinterpret_cast<unsigned*>(&Vtw[(e8 * 8 + dd) * VTS + s0]) =
            lo | (hi << 16);
      }
    }
    // zero Vt pad cols u=80..95
    #pragma unroll
    for (int z = 0; z < 8; ++z)
      *reinterpret_cast<unsigned*>(&Vtw[lane * VTS + 80 + z * 2]) = 0u;
    // cnt build (shared by both waves, cooperative)
    if (t0 >= 64) {
      #pragma unroll
      for (int e = 0; e < 8; ++e) {
        const int idx = tid + e * 128;
        const int tl = idx >> 6;
        const int rr = sel[(size_t)(t0 + tl) * KSP + (idx & 63)];
        cnt8[tl * 80 + map8[rr]] = 1;  // distinct rows per t -> no race
      }
    } else if (tid < 80) {
      // analytic multiplicities for t<64: sel(t) = rows 0..t-1 once +
      // row t x(64-t). Deterministic dup slot = t0.
      const int s = tid;
      #pragma unroll
      for (int tl = 0; tl < ATB; ++tl) {
        const int t = t0 + tl;
        int c;
        if (s < t0)        c = 1;
        else if (s == t0)  c = (tl == 0) ? (64 - t) : 1;
        else if (s < 64)   c = 0;                     // unused dup slots
        else if (s < 79) {
          const int row = t0 + 1 + (s - 64);
          c = (row < t) ? 1 : ((row == t) ? (64 - t) : 0);
        } else c = 0;                                 // pad slot
        cnt8[tl * 80 + s] = (unsigned char)c;
      }
    }
  }
  __syncthreads();

  // S^T = K @ Q^T; lane holds S[u=ut*16+qd*4+i][t=r]
  f32x4 s5[5] = {};
  #pragma unroll
  for (int ut = 0; ut < 5; ++ut) {
    #pragma unroll
    for (int kc = 0; kc < 2; ++kc) {
      const uint4 kw = *reinterpret_cast<const uint4*>(
          &Klw[(ut * 16 + r) * KLS + (((kc * 4 + qd) ^ (r & 7)) * 8)]);
      s5[ut] = __builtin_amdgcn_mfma_f32_16x16x32_f16(
          __builtin_bit_cast(half8, kw), __builtin_bit_cast(half8, qf[kc]),
          s5[ut], 0, 0, 0);
    }
  }
  // bias (mask/multiplicity) + row-max
  float mx = -3.0e38f;
  #pragma unroll
  for (int ut = 0; ut < 5; ++ut) {
    const unsigned c4 =
        *reinterpret_cast<const unsigned*>(cnt8 + r * 80 + ut * 16 + qd * 4);
    #pragma unroll
    for (int i = 0; i < 4; ++i) {
      const unsigned cc = (c4 >> (8 * i)) & 0xffu;
      float lg = s5[ut][i] * 0.125f;
      lg = (cc == 0u) ? -3.0e38f
         : (cc == 1u) ? lg : (lg + __logf((float)cc));
      s5[ut][i] = lg;
      mx = fmaxf(mx, lg);
    }
  }
  mx = fmaxf(mx, __shfl_xor(mx, 16));
  mx = fmaxf(mx, __shfl_xor(mx, 32));
  float sum = 0.f;
  #pragma unroll
  for (int ut = 0; ut < 5; ++ut)
    #pragma unroll
    for (int i = 0; i < 4; ++i) {
      const float e = __expf(s5[ut][i] - mx);
      s5[ut][i] = e;
      sum += e;
    }
  sum += __shfl_xor(sum, 16);
  sum += __shfl_xor(sum, 32);
  const float rs = 1.0f / sum;
  // barrier: cnt8/map8 (overlaid on Pl) must be fully read by BOTH waves
  // before any Pl write
  __syncthreads();
  // P -> f16 into Pl[t][u] (wave-local roundtrip)
  #pragma unroll
  for (int ut = 0; ut < 5; ++ut) {
    const unsigned w0 = (unsigned)f2h(s5[ut][0] * rs) |
                        ((unsigned)f2h(s5[ut][1] * rs) << 16);
    const unsigned w1 = (unsigned)f2h(s5[ut][2] * rs) |
                        ((unsigned)f2h(s5[ut][3] * rs) << 16);
    unsigned* p32 = reinterpret_cast<unsigned*>(&Plw[r * PLS + ut * 16 + qd * 4]);
    p32[0] = w0;
    p32[1] = w1;
  }
  // zero Pl pad u=80..95 (4 shorts per quad)
  *reinterpret_cast<unsigned long long*>(&Plw[r * PLS + 80 + qd * 4]) = 0ull;
  // PV: O^T[d][t] = Vt @ P; A = Vt rows (d), B = Pl cols (t)
  f32x4 o4[4] = {};
  #pragma unroll
  for (int c = 0; c < 3; ++c) {
    const uint4 pw = *reinterpret_cast<const uint4*>(&Plw[r * PLS + c * 32 + qd * 8]);
    #pragma unroll
    for (int mt = 0; mt < 4; ++mt) {
      const unsigned short* vb_ = &Vtw[(mt * 16 + r) * VTS + c * 32 + qd * 8];
      uint4 vw;
      vw.x = *reinterpret_cast<const unsigned*>(vb_);
      vw.y = *reinterpret_cast<const unsigned*>(vb_ + 2);
      vw.z = *reinterpret_cast<const unsigned*>(vb_ + 4);
      vw.w = *reinterpret_cast<const unsigned*>(vb_ + 6);
      o4[mt] = __builtin_amdgcn_mfma_f32_16x16x32_f16(
          __builtin_bit_cast(half8, vw), __builtin_bit_cast(half8, pw),
          o4[mt], 0, 0, 0);
    }
  }
  // store: lane holds O[t=r][d = mt*16 + qd*4 + i], bf16 out
  #pragma unroll
  for (int mt = 0; mt < 4; ++mt) {
    ushort4 ov;
    ov.x = f2bfu(o4[mt][0]); ov.y = f2bfu(o4[mt][1]);
    ov.z = f2bfu(o4[mt][2]); ov.w = f2bfu(o4[mt][3]);
    *reinterpret_cast<ushort4*>(
        attn_out + (size_t)(t0 + r) * C_DIM + h * HS + mt * 16 + qd * 4) = ov;
  }
}

extern "C" void kernel_launch(void* const* d_in, const int* in_sizes, int n_in,
                              void* d_out, int out_size, void* d_ws, size_t ws_size,
                              hipStream_t stream) {
  const float* x   = (const float*)d_in[0];
  const float* Wq  = (const float*)d_in[1];
  const float* bq  = (const float*)d_in[2];
  const float* Wk  = (const float*)d_in[3];
  const float* bk  = (const float*)d_in[4];
  const float* Wv  = (const float*)d_in[5];
  const float* bv  = (const float*)d_in[6];
  const float* Wo  = (const float*)d_in[7];
  const float* bo  = (const float*)d_in[8];
  const float* Wks = (const float*)d_in[9];
  const float* bks = (const float*)d_in[10];
  float* out = (float*)d_out;

  char* ws = (char*)d_ws;
  size_t off = 0;
  float* scores = (float*)(ws + off); off += 8192;
  int*   sorted = (int*)(ws + off);   off += 8192;
  unsigned short* selb = (unsigned short*)(ws + off); off += (size_t)T_DIM * KSP * 2;
  unsigned short* xb  = (unsigned short*)(ws + off); off += (size_t)T_DIM * C_DIM * 2;
  unsigned short* Wqb = (unsigned short*)(ws + off); off += (size_t)C_DIM * C_DIM * 2;
  unsigned short* Wkb = (unsigned short*)(ws + off); off += (size_t)C_DIM * C_DIM * 2;
  unsigned short* Wvb = (unsigned short*)(ws + off); off += (size_t)C_DIM * C_DIM * 2;
  unsigned short* Wob = (unsigned short*)(ws + off); off += (size_t)C_DIM * C_DIM * 2;
  unsigned short* qb  = (unsigned short*)(ws + off); off += (size_t)T_DIM * C_DIM * 2;
  unsigned short* kb  = (unsigned short*)(ws + off); off += (size_t)T_DIM * C_DIM * 2;
  unsigned short* vb  = (unsigned short*)(ws + off); off += (size_t)T_DIM * C_DIM * 2;
  unsigned short* ab  = xb;  // alias: xb dead after gemm_qkv

  // launch 1: conversion + scores
  convert_scores_kernel<<<NSCORE + NCONV, 256, 0, stream>>>(
      x, Wq, Wk, Wv, Wo, Wks, bks, xb, Wqb, Wkb, Wvb, Wob, scores);

  // launch 2: rank-sort (512 blocks) + fused QKV GEMM (768 blocks)
  gemm_qkv_rank_kernel<<<NRANK + 3 * (T_DIM / GBM) * (C_DIM / GBN), 256, 0,
                         stream>>>(
      xb, Wqb, Wkb, Wvb, bq, bk, bv, qb, kb, vb, scores, sorted);

  // launch 3: per-t top-64 selection (one wave per t)
  select_kernel<<<T_DIM / 4, 256, 0, stream>>>(sorted, selb);

  // launch 4: MFMA attention (128 t-tiles x 8 head-pairs = 1024 blocks)
  attn_kernel<<<(T_DIM / ATB) * (NH / 2), 128, 0, stream>>>(qb, kb, vb, selb, ab);

  // launch 5: output projection (512 blocks, 64x64)
  gemm_o_f32_kernel<<<(T_DIM / OBM) * (C_DIM / OBN), 256, 0, stream>>>(
      ab, Wob, bo, out);
}

// Round 9
// 145.961 us; speedup vs baseline: 1.0714x; 1.0037x over previous
//
#include <hip/hip_runtime.h>
#include <hip/hip_bf16.h>
#include <cstdint>
#include <cstddef>

#define T_DIM 2048
#define C_DIM 1024
#define NH 16
#define HS 64
#define KSP 64

// QKV GEMM: 128x64 tile, BK=128, XOR-swizzled LDS, global_load_lds staging
#define GBM 128
#define GBN 64
#define GBK 128
// o-proj GEMM: 64x64 tile (512 blocks = 2/CU) — R6 config (128x64 @1/CU regressed)
#define OBM 64
#define OBN 64

// attention tiling: ATB=16 consecutive t's per block, 2 heads (1 per wave).
// union(tile) = sel(t0) UNION {t0+1..t0+15} (prefix property) -> positional
// slots 0..78; slot 79 = pad (row t0 data, cnt=0 -> masked).
// R9: K staged direct-to-register (A-fragment = one uint4/lane from global);
// Kl LDS removed -> 32.4 KB arena -> 5 blocks/CU (was 3).
#define ATB 16
#define VTS 102   // Vt row stride (shorts): odd u32-stride 51 -> ~2-way
#define PLS 96    // Pl row stride (shorts): 192B, 16B-aligned b128 reads

typedef short short8 __attribute__((ext_vector_type(8)));
typedef float f32x4 __attribute__((ext_vector_type(4)));
typedef _Float16 half8 __attribute__((ext_vector_type(8)));

__device__ __forceinline__ unsigned short f2bfu(float f) {
  unsigned u = __builtin_bit_cast(unsigned, f);
  unsigned r = (u + 0x7fffu + ((u >> 16) & 1u)) >> 16;
  return (unsigned short)r;
}
__device__ __forceinline__ unsigned short f2h(float f) {
  _Float16 h = (_Float16)f;
  return __builtin_bit_cast(unsigned short, h);
}

#define GLOAD_LDS16(gp, lp)                                                  \
  __builtin_amdgcn_global_load_lds(                                          \
      (const __attribute__((address_space(1))) void*)(gp),                   \
      (__attribute__((address_space(3))) void*)(lp), 16, 0, 0)

// ---- launch 1: key_scores (blocks [0,512)) + f32->bf16 conversion (rest) ----
#define NSCORE (T_DIM / 4)  // 512
#define NCONV ((T_DIM * C_DIM + 4 * C_DIM * C_DIM) / 4 / 256)  // 6144
__global__ __launch_bounds__(256) void convert_scores_kernel(
    const float* __restrict__ x, const float* __restrict__ Wq,
    const float* __restrict__ Wk, const float* __restrict__ Wv,
    const float* __restrict__ Wo, const float* __restrict__ Wks,
    const float* __restrict__ bks,
    unsigned short* __restrict__ xb, unsigned short* __restrict__ Wqb,
    unsigned short* __restrict__ Wkb, unsigned short* __restrict__ Wvb,
    unsigned short* __restrict__ Wob, float* __restrict__ scores) {
  if (blockIdx.x < NSCORE) {
    const int t = blockIdx.x * 4 + (threadIdx.x >> 6);
    const int lane = threadIdx.x & 63;
    const float* xrow = x + (size_t)t * C_DIM;
    float acc = 0.f;
    #pragma unroll 4
    for (int i = lane; i < C_DIM; i += 64)
      acc += xrow[i] * Wks[i];
    #pragma unroll
    for (int o = 32; o; o >>= 1) acc += __shfl_xor(acc, o);
    if (lane == 0) scores[t] = acc + bks[0];
    return;
  }
  const int i = (blockIdx.x - NSCORE) * 256 + threadIdx.x;
  const int NX4 = T_DIM * C_DIM / 4;
  const int NW4 = C_DIM * C_DIM / 4;
  const float* src;
  unsigned short* dst;
  int j = i;
  if (j < NX4) { src = x; dst = xb; }
  else {
    j -= NX4;
    int w = j / NW4;
    j -= w * NW4;
    src = (w == 0) ? Wq : (w == 1) ? Wk : (w == 2) ? Wv : Wo;
    dst = (w == 0) ? Wqb : (w == 1) ? Wkb : (w == 2) ? Wvb : Wob;
  }
  float4 f = reinterpret_cast<const float4*>(src)[j];
  ushort4 o;
  o.x = f2bfu(f.x); o.y = f2bfu(f.y); o.z = f2bfu(f.z); o.w = f2bfu(f.w);
  reinterpret_cast<ushort4*>(dst)[j] = o;
}

// ---- GEMM body: 128x64 tile, BK=128; LDS passed in (shared arena) ----
__device__ __forceinline__ void gemm_body_128x64(
    const unsigned short* __restrict__ A, const unsigned short* __restrict__ W,
    f32x4 acc[4][2], int bm, int bn, int tid,
    unsigned short* As, unsigned short* Ws) {
  const int w = tid >> 6, lane = tid & 63;
  const int quad = lane >> 4, r = lane & 15;
  const int wm = (w >> 1) * 64, wn = (w & 1) * 32;
  const int sub = lane >> 4;
  const int c = lane & 15;
  const unsigned short* Arow[8];
  const unsigned short* Wrow[4];
  #pragma unroll
  for (int i = 0; i < 8; ++i) {
    const int row = w * 32 + i * 4 + sub;
    Arow[i] = A + (size_t)(bm * GBM + row) * C_DIM + ((c ^ (row & 7)) * 8);
  }
  #pragma unroll
  for (int i = 0; i < 4; ++i) {
    const int row = w * 16 + i * 4 + sub;
    Wrow[i] = W + (size_t)(bn * GBN + row) * C_DIM + ((c ^ (row & 7)) * 8);
  }
  for (int kb = 0; kb < C_DIM; kb += GBK) {
    #pragma unroll
    for (int i = 0; i < 8; ++i)
      GLOAD_LDS16(Arow[i] + kb, &As[(w * 32 + i * 4) * GBK]);
    #pragma unroll
    for (int i = 0; i < 4; ++i)
      GLOAD_LDS16(Wrow[i] + kb, &Ws[(w * 16 + i * 4) * GBK]);
    __syncthreads();
    #pragma unroll
    for (int ks = 0; ks < 4; ++ks) {
      const int pc = ((ks * 4 + quad) ^ (r & 7)) * 8;
      short8 af[4], bfr[2];
      #pragma unroll
      for (int mi = 0; mi < 4; ++mi)
        af[mi] = *reinterpret_cast<const short8*>(&As[(wm + mi * 16 + r) * GBK + pc]);
      #pragma unroll
      for (int ni = 0; ni < 2; ++ni)
        bfr[ni] = *reinterpret_cast<const short8*>(&Ws[(wn + ni * 16 + r) * GBK + pc]);
      #pragma unroll
      for (int mi = 0; mi < 4; ++mi)
        #pragma unroll
        for (int ni = 0; ni < 2; ++ni)
          acc[mi][ni] = __builtin_amdgcn_mfma_f32_16x16x32_bf16(af[mi], bfr[ni], acc[mi][ni], 0, 0, 0);
    }
    __syncthreads();
  }
}

// ---- launch 2: rank_sort (blocks [0,512)) + fused QKV GEMM (rest). ----
#define NRANK (T_DIM / 4)  // 512
__global__ __launch_bounds__(256) void gemm_qkv_rank_kernel(
    const unsigned short* __restrict__ A,
    const unsigned short* __restrict__ Wq, const unsigned short* __restrict__ Wk,
    const unsigned short* __restrict__ Wv,
    const float* __restrict__ bq, const float* __restrict__ bk,
    const float* __restrict__ bv,
    unsigned short* __restrict__ qo, unsigned short* __restrict__ ko,
    unsigned short* __restrict__ vo,
    const float* __restrict__ scores, int* __restrict__ sorted_idx) {
  __shared__ unsigned short lds[(GBM + GBN) * GBK];  // 48 KB arena
  const int tid = threadIdx.x;
  if (blockIdx.x < NRANK) {
    // rank-by-counting sort: one wave per element, lane-parallel scan
    float* ss = reinterpret_cast<float*>(lds);  // first 8 KB of arena
    for (int j = tid; j < T_DIM; j += 256) ss[j] = scores[j];
    __syncthreads();
    const int w = tid >> 6, lane = tid & 63;
    const int i = blockIdx.x * 4 + w;
    const float si = ss[i];
    int rank = 0;
    #pragma unroll
    for (int step = 0; step < T_DIM / 64; ++step) {
      const int j = step * 64 + lane;
      const float sj = ss[j];
      rank += (int)((sj > si) || (sj == si && j < i));
    }
    #pragma unroll
    for (int o = 32; o; o >>= 1) rank += __shfl_xor(rank, o);
    if (lane == 0) sorted_idx[rank] = i;
    return;
  }
  const int bid = blockIdx.x - NRANK;
  const int per = (T_DIM / GBM) * (C_DIM / GBN);  // 256
  const int which = bid / per;
  const int rem = bid % per;
  const int bm = rem / (C_DIM / GBN);
  const int bn = rem % (C_DIM / GBN);
  const unsigned short* W = (which == 0) ? Wq : (which == 1) ? Wk : Wv;
  const float* bias = (which == 0) ? bq : (which == 1) ? bk : bv;
  unsigned short* out = (which == 0) ? qo : (which == 1) ? ko : vo;
  f32x4 acc[4][2] = {};
  gemm_body_128x64(A, W, acc, bm, bn, tid, lds, lds + GBM * GBK);
  const int w = tid >> 6, lane = tid & 63;
  const int quad = lane >> 4, r = lane & 15;
  const int wm = (w >> 1) * 64, wn = (w & 1) * 32;
  #pragma unroll
  for (int mi = 0; mi < 4; ++mi) {
    #pragma unroll
    for (int ni = 0; ni < 2; ++ni) {
      const int col = bn * GBN + wn + ni * 16 + r;
      const float bf = bias[col];
      #pragma unroll
      for (int i = 0; i < 4; ++i) {
        const int row = bm * GBM + wm + mi * 16 + quad * 4 + i;
        const float val = acc[mi][ni][i] + bf;
        // q,k,v all f16 (MFMA f16 path in attn; f16 V >= bf16 precision)
        out[(size_t)row * C_DIM + col] = f2h(val);
      }
    }
  }
}

// ---- o-proj GEMM body: 64x64 tile, BK=128 (R6-verified) ----
__device__ __forceinline__ void gemm_body_64x64(
    const unsigned short* __restrict__ A, const unsigned short* __restrict__ W,
    f32x4 acc[2][2], int bm, int bn, int tid) {
  __shared__ unsigned short As[OBM * GBK];  // 16 KB
  __shared__ unsigned short Ws[OBN * GBK];  // 16 KB
  const int w = tid >> 6, lane = tid & 63;
  const int quad = lane >> 4, r = lane & 15;
  const int wm = (w >> 1) * 32, wn = (w & 1) * 32;
  const int sub = lane >> 4;
  const int c = lane & 15;
  const unsigned short* Arow[4];
  const unsigned short* Wrow[4];
  #pragma unroll
  for (int i = 0; i < 4; ++i) {
    const int row = w * 16 + i * 4 + sub;
    Arow[i] = A + (size_t)(bm * OBM + row) * C_DIM + ((c ^ (row & 7)) * 8);
    Wrow[i] = W + (size_t)(bn * OBN + row) * C_DIM + ((c ^ (row & 7)) * 8);
  }
  for (int kb = 0; kb < C_DIM; kb += GBK) {
    #pragma unroll
    for (int i = 0; i < 4; ++i)
      GLOAD_LDS16(Arow[i] + kb, &As[(w * 16 + i * 4) * GBK]);
    #pragma unroll
    for (int i = 0; i < 4; ++i)
      GLOAD_LDS16(Wrow[i] + kb, &Ws[(w * 16 + i * 4) * GBK]);
    __syncthreads();
    #pragma unroll
    for (int ks = 0; ks < 4; ++ks) {
      const int pc = ((ks * 4 + quad) ^ (r & 7)) * 8;
      short8 af[2], bfr[2];
      #pragma unroll
      for (int mi = 0; mi < 2; ++mi)
        af[mi] = *reinterpret_cast<const short8*>(&As[(wm + mi * 16 + r) * GBK + pc]);
      #pragma unroll
      for (int ni = 0; ni < 2; ++ni)
        bfr[ni] = *reinterpret_cast<const short8*>(&Ws[(wn + ni * 16 + r) * GBK + pc]);
      #pragma unroll
      for (int mi = 0; mi < 2; ++mi)
        #pragma unroll
        for (int ni = 0; ni < 2; ++ni)
          acc[mi][ni] = __builtin_amdgcn_mfma_f32_16x16x32_bf16(af[mi], bfr[ni], acc[mi][ni], 0, 0, 0);
    }
    __syncthreads();
  }
}

// ---- launch 5: output projection GEMM, fp32 out, 64x64 tile ----
__global__ __launch_bounds__(256) void gemm_o_f32_kernel(
    const unsigned short* __restrict__ A, const unsigned short* __restrict__ W,
    const float* __restrict__ bias, float* __restrict__ out) {
  const int tid = threadIdx.x;
  const int bm = blockIdx.x / (C_DIM / OBN);
  const int bn = blockIdx.x % (C_DIM / OBN);
  f32x4 acc[2][2] = {};
  gemm_body_64x64(A, W, acc, bm, bn, tid);
  const int w = tid >> 6, lane = tid & 63;
  const int quad = lane >> 4, r = lane & 15;
  const int wm = (w >> 1) * 32, wn = (w & 1) * 32;
  #pragma unroll
  for (int mi = 0; mi < 2; ++mi) {
    #pragma unroll
    for (int ni = 0; ni < 2; ++ni) {
      const int col = bn * OBN + wn + ni * 16 + r;
      const float bf = bias[col];
      #pragma unroll
      for (int i = 0; i < 4; ++i) {
        const int row = bm * OBM + wm + mi * 16 + quad * 4 + i;
        out[(size_t)row * C_DIM + col] = acc[mi][ni][i] + bf;
      }
    }
  }
}

// ---- launch 3: per-t top-64 selection (one wave per t, u16 row indices) ----
__global__ __launch_bounds__(256) void select_kernel(
    const int* __restrict__ sorted_idx, unsigned short* __restrict__ sel) {
  const int tid = threadIdx.x;
  const int w = tid >> 6, lane = tid & 63;
  const int t = blockIdx.x * 4 + w;
  unsigned short* dst = sel + (size_t)t * KSP;
  if (t <= 63) {
    // reference semantics: rows 0..t-1 once, row t duplicated (clamped -inf picks)
    dst[lane] = (unsigned short)((lane < t) ? lane : t);
    return;
  }
  const unsigned long long lt_mask = (1ull << lane) - 1ull;
  int count = 0;
  for (int c = 0; c < T_DIM / 64 && count < KSP; ++c) {
    int s = sorted_idx[c * 64 + lane];
    s = (s < 0) ? 0 : (s > T_DIM - 1 ? T_DIM - 1 : s);
    const bool ok = (s <= t);
    const unsigned long long mm = __ballot(ok);
    const int pos = count + __popcll(mm & lt_mask);
    if (ok && pos < KSP) dst[pos] = (unsigned short)s;
    count += __popcll(mm);
  }
}

// ---- launch 4: MFMA sparse attention, K direct-to-register.
// 32.4 KB arena (Vt + Pl/overlay + urows) -> 5 blocks/CU x 2 waves = 10
// waves/CU (was 6). K QK^T A-fragments are one uint4/lane from global
// (identical scatter granularity as the old LDS stage, same values/order
// -> bit-identical output). Vt stays LDS (transpose required for PV). ----
__global__ __launch_bounds__(128) void attn_kernel(
    const unsigned short* __restrict__ q, const unsigned short* __restrict__ k,
    const unsigned short* __restrict__ v, const unsigned short* __restrict__ sel,
    unsigned short* __restrict__ attn_out) {
  // arena carve:
  //   [0,26112)      Vt: 2 x 64 x 102 shorts
  //   [26112,32256)  Pl: 2 x 16 x 96 shorts; overlay map8[2048]+cnt8[1280]
  //   [32256,32416)  urows[80]
  __shared__ __align__(16) unsigned char arena[32416];
  unsigned short* VtB = reinterpret_cast<unsigned short*>(arena);
  unsigned short* PlB = reinterpret_cast<unsigned short*>(arena + 26112);
  unsigned char* map8 = arena + 26112;
  unsigned char* cnt8 = arena + 26112 + 2048;
  unsigned short* urows = reinterpret_cast<unsigned short*>(arena + 32256);
  const int tb = blockIdx.x >> 3;
  const int hg = blockIdx.x & 7;
  const int t0 = tb * ATB;
  const int tid = threadIdx.x;
  const int w = tid >> 6, lane = tid & 63;
  const int qd = lane >> 4;      // quad
  const int r = lane & 15;
  const int h = hg * 2 + w;
  unsigned short* Vtw = VtB + w * 64 * VTS;
  unsigned short* Plw = PlB + w * 16 * PLS;

  // hoist Q B-frags (global f16): lane (qd,r) holds Q[t0+r][kc*32+qd*8 ..+7]
  uint4 qf[2];
  #pragma unroll
  for (int kc = 0; kc < 2; ++kc)
    qf[kc] = *reinterpret_cast<const uint4*>(
        q + (size_t)(t0 + r) * C_DIM + h * HS + kc * 32 + qd * 8);

  // phase A: positional union (slots 0..78 + pad 79), map build (t0>=64),
  // cnt zero-init (t0>=64 path only; analytic path overwrites all entries)
  if (tid < KSP) {
    const int r0 = sel[(size_t)t0 * KSP + tid];
    urows[tid] = (unsigned short)r0;
    if (t0 >= 64) map8[r0] = (unsigned char)tid;  // rows distinct -> no race
  } else if (tid < 79) {
    const int row = t0 + 1 + (tid - KSP);
    urows[tid] = (unsigned short)row;
    if (t0 >= 64) map8[row] = (unsigned char)tid;
  } else if (tid == 79) {
    urows[79] = (unsigned short)t0;   // pad slot: real data, cnt=0 -> masked
  }
  if (t0 >= 64) {
    for (int i = tid; i < 320; i += 128)
      reinterpret_cast<unsigned*>(cnt8)[i] = 0u;
  }
  __syncthreads();

  // K A-frags direct from global: lane (qd,r) holds K[urows[ut*16+r]][kc*32+qd*8..+7]
  uint4 kf[5][2];
  #pragma unroll
  for (int ut = 0; ut < 5; ++ut) {
    const int rowg = urows[ut * 16 + r];
    const unsigned short* kr = k + (size_t)rowg * C_DIM + h * HS + qd * 8;
    kf[ut][0] = *reinterpret_cast<const uint4*>(kr);
    kf[ut][1] = *reinterpret_cast<const uint4*>(kr + 32);
  }

  // phase B: per-wave V gather/transpose + cooperative cnt build
  {
    const int e8 = lane & 7;
    const int pr = lane >> 3;  // row-pair id 0..7
    #pragma unroll
    for (int sb = 0; sb < 5; ++sb) {
      const int s0 = sb * 16 + pr * 2;
      const int row0 = urows[s0], row1 = urows[s0 + 1];
      const size_t g0 = (size_t)row0 * C_DIM + h * HS + e8 * 8;
      const size_t g1 = (size_t)row1 * C_DIM + h * HS + e8 * 8;
      const uint4 v0 = *reinterpret_cast<const uint4*>(v + g0);
      const uint4 v1 = *reinterpret_cast<const uint4*>(v + g1);
      const unsigned* v0w = reinterpret_cast<const unsigned*>(&v0);
      const unsigned* v1w = reinterpret_cast<const unsigned*>(&v1);
      // transpose-scatter: Vt[d][s0..s0+1] as one u32 (pair-packed)
      #pragma unroll
      for (int dd = 0; dd < 8; ++dd) {
        const unsigned lo = (v0w[dd >> 1] >> ((dd & 1) * 16)) & 0xffffu;
        const unsigned hi = (v1w[dd >> 1] >> ((dd & 1) * 16)) & 0xffffu;
        *reinterpret_cast<unsigned*>(&Vtw[(e8 * 8 + dd) * VTS + s0]) =
            lo | (hi << 16);
      }
    }
    // zero Vt pad cols u=80..95
    #pragma unroll
    for (int z = 0; z < 8; ++z)
      *reinterpret_cast<unsigned*>(&Vtw[lane * VTS + 80 + z * 2]) = 0u;
    // cnt build (shared by both waves, cooperative)
    if (t0 >= 64) {
      #pragma unroll
      for (int e = 0; e < 8; ++e) {
        const int idx = tid + e * 128;
        const int tl = idx >> 6;
        const int rr = sel[(size_t)(t0 + tl) * KSP + (idx & 63)];
        cnt8[tl * 80 + map8[rr]] = 1;  // distinct rows per t -> no race
      }
    } else if (tid < 80) {
      // analytic multiplicities for t<64: sel(t) = rows 0..t-1 once +
      // row t x(64-t). Deterministic dup slot = t0.
      const int s = tid;
      #pragma unroll
      for (int tl = 0; tl < ATB; ++tl) {
        const int t = t0 + tl;
        int c;
        if (s < t0)        c = 1;
        else if (s == t0)  c = (tl == 0) ? (64 - t) : 1;
        else if (s < 64)   c = 0;                     // unused dup slots
        else if (s < 79) {
          const int row = t0 + 1 + (s - 64);
          c = (row < t) ? 1 : ((row == t) ? (64 - t) : 0);
        } else c = 0;                                 // pad slot
        cnt8[tl * 80 + s] = (unsigned char)c;
      }
    }
  }
  __syncthreads();

  // S^T = K @ Q^T; lane holds S[u=ut*16+qd*4+i][t=r]
  f32x4 s5[5] = {};
  #pragma unroll
  for (int ut = 0; ut < 5; ++ut) {
    #pragma unroll
    for (int kc = 0; kc < 2; ++kc) {
      s5[ut] = __builtin_amdgcn_mfma_f32_16x16x32_f16(
          __builtin_bit_cast(half8, kf[ut][kc]), __builtin_bit_cast(half8, qf[kc]),
          s5[ut], 0, 0, 0);
    }
  }
  // bias (mask/multiplicity) + row-max
  float mx = -3.0e38f;
  #pragma unroll
  for (int ut = 0; ut < 5; ++ut) {
    const unsigned c4 =
        *reinterpret_cast<const unsigned*>(cnt8 + r * 80 + ut * 16 + qd * 4);
    #pragma unroll
    for (int i = 0; i < 4; ++i) {
      const unsigned cc = (c4 >> (8 * i)) & 0xffu;
      float lg = s5[ut][i] * 0.125f;
      lg = (cc == 0u) ? -3.0e38f
         : (cc == 1u) ? lg : (lg + __logf((float)cc));
      s5[ut][i] = lg;
      mx = fmaxf(mx, lg);
    }
  }
  mx = fmaxf(mx, __shfl_xor(mx, 16));
  mx = fmaxf(mx, __shfl_xor(mx, 32));
  float sum = 0.f;
  #pragma unroll
  for (int ut = 0; ut < 5; ++ut)
    #pragma unroll
    for (int i = 0; i < 4; ++i) {
      const float e = __expf(s5[ut][i] - mx);
      s5[ut][i] = e;
      sum += e;
    }
  sum += __shfl_xor(sum, 16);
  sum += __shfl_xor(sum, 32);
  const float rs = 1.0f / sum;
  // barrier: cnt8/map8 (overlaid on Pl) must be fully read by BOTH waves
  // before any Pl write
  __syncthreads();
  // P -> f16 into Pl[t][u] (wave-local roundtrip)
  #pragma unroll
  for (int ut = 0; ut < 5; ++ut) {
    const unsigned w0 = (unsigned)f2h(s5[ut][0] * rs) |
                        ((unsigned)f2h(s5[ut][1] * rs) << 16);
    const unsigned w1 = (unsigned)f2h(s5[ut][2] * rs) |
                        ((unsigned)f2h(s5[ut][3] * rs) << 16);
    unsigned* p32 = reinterpret_cast<unsigned*>(&Plw[r * PLS + ut * 16 + qd * 4]);
    p32[0] = w0;
    p32[1] = w1;
  }
  // zero Pl pad u=80..95 (4 shorts per quad)
  *reinterpret_cast<unsigned long long*>(&Plw[r * PLS + 80 + qd * 4]) = 0ull;
  // PV: O^T[d][t] = Vt @ P; A = Vt rows (d), B = Pl cols (t)
  f32x4 o4[4] = {};
  #pragma unroll
  for (int c = 0; c < 3; ++c) {
    const uint4 pw = *reinterpret_cast<const uint4*>(&Plw[r * PLS + c * 32 + qd * 8]);
    #pragma unroll
    for (int mt = 0; mt < 4; ++mt) {
      const unsigned short* vb_ = &Vtw[(mt * 16 + r) * VTS + c * 32 + qd * 8];
      uint4 vw;
      vw.x = *reinterpret_cast<const unsigned*>(vb_);
      vw.y = *reinterpret_cast<const unsigned*>(vb_ + 2);
      vw.z = *reinterpret_cast<const unsigned*>(vb_ + 4);
      vw.w = *reinterpret_cast<const unsigned*>(vb_ + 6);
      o4[mt] = __builtin_amdgcn_mfma_f32_16x16x32_f16(
          __builtin_bit_cast(half8, vw), __builtin_bit_cast(half8, pw),
          o4[mt], 0, 0, 0);
    }
  }
  // store: lane holds O[t=r][d = mt*16 + qd*4 + i], bf16 out
  #pragma unroll
  for (int mt = 0; mt < 4; ++mt) {
    ushort4 ov;
    ov.x = f2bfu(o4[mt][0]); ov.y = f2bfu(o4[mt][1]);
    ov.z = f2bfu(o4[mt][2]); ov.w = f2bfu(o4[mt][3]);
    *reinterpret_cast<ushort4*>(
        attn_out + (size_t)(t0 + r) * C_DIM + h * HS + mt * 16 + qd * 4) = ov;
  }
}

extern "C" void kernel_launch(void* const* d_in, const int* in_sizes, int n_in,
                              void* d_out, int out_size, void* d_ws, size_t ws_size,
                              hipStream_t stream) {
  const float* x   = (const float*)d_in[0];
  const float* Wq  = (const float*)d_in[1];
  const float* bq  = (const float*)d_in[2];
  const float* Wk  = (const float*)d_in[3];
  const float* bk  = (const float*)d_in[4];
  const float* Wv  = (const float*)d_in[5];
  const float* bv  = (const float*)d_in[6];
  const float* Wo  = (const float*)d_in[7];
  const float* bo  = (const float*)d_in[8];
  const float* Wks = (const float*)d_in[9];
  const float* bks = (const float*)d_in[10];
  float* out = (float*)d_out;

  char* ws = (char*)d_ws;
  size_t off = 0;
  float* scores = (float*)(ws + off); off += 8192;
  int*   sorted = (int*)(ws + off);   off += 8192;
  unsigned short* selb = (unsigned short*)(ws + off); off += (size_t)T_DIM * KSP * 2;
  unsigned short* xb  = (unsigned short*)(ws + off); off += (size_t)T_DIM * C_DIM * 2;
  unsigned short* Wqb = (unsigned short*)(ws + off); off += (size_t)C_DIM * C_DIM * 2;
  unsigned short* Wkb = (unsigned short*)(ws + off); off += (size_t)C_DIM * C_DIM * 2;
  unsigned short* Wvb = (unsigned short*)(ws + off); off += (size_t)C_DIM * C_DIM * 2;
  unsigned short* Wob = (unsigned short*)(ws + off); off += (size_t)C_DIM * C_DIM * 2;
  unsigned short* qb  = (unsigned short*)(ws + off); off += (size_t)T_DIM * C_DIM * 2;
  unsigned short* kb  = (unsigned short*)(ws + off); off += (size_t)T_DIM * C_DIM * 2;
  unsigned short* vb  = (unsigned short*)(ws + off); off += (size_t)T_DIM * C_DIM * 2;
  unsigned short* ab  = xb;  // alias: xb dead after gemm_qkv

  // launch 1: conversion + scores
  convert_scores_kernel<<<NSCORE + NCONV, 256, 0, stream>>>(
      x, Wq, Wk, Wv, Wo, Wks, bks, xb, Wqb, Wkb, Wvb, Wob, scores);

  // launch 2: rank-sort (512 blocks) + fused QKV GEMM (768 blocks)
  gemm_qkv_rank_kernel<<<NRANK + 3 * (T_DIM / GBM) * (C_DIM / GBN), 256, 0,
                         stream>>>(
      xb, Wqb, Wkb, Wvb, bq, bk, bv, qb, kb, vb, scores, sorted);

  // launch 3: per-t top-64 selection (one wave per t)
  select_kernel<<<T_DIM / 4, 256, 0, stream>>>(sorted, selb);

  // launch 4: MFMA attention (128 t-tiles x 8 head-pairs = 1024 blocks)
  attn_kernel<<<(T_DIM / ATB) * (NH / 2), 128, 0, stream>>>(qb, kb, vb, selb, ab);

  // launch 5: output projection (512 blocks, 64x64)
  gemm_o_f32_kernel<<<(T_DIM / OBM) * (C_DIM / OBN), 256, 0, stream>>>(
      ab, Wob, bo, out);
}